// Round 4
// baseline (634.301 us; speedup 1.0000x reference)
//
#include <hip/hip_runtime.h>
#include <stdint.h>

#define B_ 32
#define N_ 4096
#define D_ 512
#define K_ 64
#define M_ (B_ * N_)        // 131072 total tokens
#define NS 16               // n-splits (blocks per batch) for fused kernel
#define CPB 8               // 32-token chunks per block (256 tokens / 32)

typedef float f32x4 __attribute__((ext_vector_type(4)));
typedef short bf16x8 __attribute__((ext_vector_type(8)));
typedef uint32_t u32;

union U8 { u32 u[4]; bf16x8 v; uint4 q4; };

// low16 = bf16_trunc(a), high16 = bf16_trunc(b)
__device__ __forceinline__ u32 pack_hi2(float a, float b) {
    return __builtin_amdgcn_perm(__float_as_uint(b), __float_as_uint(a), 0x07060302u);
}
// gather low16 halves of (p0,p1) -> u32
__device__ __forceinline__ u32 lo16s(u32 p0, u32 p1) {
    return __builtin_amdgcn_perm(p1, p0, 0x05040100u);
}
// gather high16 halves of (p0,p1) -> u32
__device__ __forceinline__ u32 hi16s(u32 p0, u32 p1) {
    return __builtin_amdgcn_perm(p1, p0, 0x07060302u);
}
__device__ __forceinline__ float trunc_hi(float f) {
    return __uint_as_float(__float_as_uint(f) & 0xffff0000u);
}

// XOR swizzle (16B granule) for the xp tile. val = j ^ q ^ (q<<2) puts the
// tok-quarter's low bit into bank-half (byte bit 4+2) -> vlad b32 gathers
// spread 2 lanes/bank; logits b128 row reads stay uniform over all 8 slots.
__device__ __forceinline__ int xswb2(int tok) {
    return (((tok & 7) ^ (tok >> 3) ^ ((tok >> 3) << 2)) << 4);
}

// ---------------------------------------------------------------------------
// Prep: clusters (D x K) -> frag-ordered bf16 hi/lo arrays (unchanged).
// cfh/cfl[(t*4 + c)*64 + lane] elem j = B[t*32 + (lane>>4)*8 + j][c*16 + (lane&15)]
// ---------------------------------------------------------------------------
__global__ void k_prep(const float* __restrict__ clusters,
                       bf16x8* __restrict__ cfh, bf16x8* __restrict__ cfl)
{
    const int t = blockIdx.x;        // 0..15 k-chunk (32 wide)
    const int c = blockIdx.y;        // 0..3  col tile (16 wide)
    const int lane = threadIdx.x;    // 0..63
    const int q = lane >> 4, li = lane & 15;
    U8 h, l;
    #pragma unroll
    for (int j2 = 0; j2 < 4; ++j2) {
        float v0 = clusters[(t*32 + q*8 + 2*j2 + 0) * K_ + c*16 + li];
        float v1 = clusters[(t*32 + q*8 + 2*j2 + 1) * K_ + c*16 + li];
        float l0 = v0 - trunc_hi(v0), l1 = v1 - trunc_hi(v1);
        h.u[j2] = pack_hi2(v0, v1);
        l.u[j2] = pack_hi2(l0, l1);
    }
    cfh[(t*4 + c)*64 + lane] = h.v;
    cfl[(t*4 + c)*64 + lane] = l.v;
}

// ---------------------------------------------------------------------------
// Fused kernel, v3: x staged ONCE per chunk as pair-packed u32 (hi-bf16 in
// low16, lo-bf16 in high16) -> conversion done once at stage time; logits
// and vlad both consume packed pairs with cheap perm unpack. Single 64 KB
// buffer => 74 KB LDS => 2 blocks/CU (2 waves/SIMD) for latency hiding.
// Wave roles: stage — rows w*8..w*8+7; logits — c-tile w (16 cols, all 32
// tok); vlad — d-range [w*128, w*128+128) for all 64 k.
// Grid (NS=16, B_=32) = 512 blocks, 256 threads.
// ---------------------------------------------------------------------------
__global__ __launch_bounds__(256, 2) void k_fused(
    const float* __restrict__ x,
    const bf16x8* __restrict__ cfh, const bf16x8* __restrict__ cfl,
    const float* __restrict__ bnw, const float* __restrict__ bnb,
    const float* __restrict__ rm, const float* __restrict__ rv,
    float* __restrict__ part, float* __restrict__ a_sum)
{
    const int tid  = threadIdx.x;
    const int w    = tid >> 6, lane = tid & 63;
    const int q    = lane >> 4, li = lane & 15;
    const int s    = blockIdx.x, b = blockIdx.y;
    const size_t n0 = (size_t)b * N_ + (size_t)s * (N_ / NS);

    __shared__ __align__(16) u32 xp[32 * 512];     // 64 KB packed pairs, swizzled
    __shared__ __align__(16) u32 at[64 * 36];      // 9 KB aT[k][tok], stride 144 B
    __shared__ float red[32][4];                   // per-token partial denoms

    // BN(eval) coefficients: this wave's single c-tile, col = w*16 + li
    const int col = w*16 + li;
    const float alpha = bnw[col] * rsqrtf(rv[col] + 1e-5f);
    const float beta  = bnb[col] - rm[col] * alpha;

    // cf fragments for this wave's c-tile: 16 t-steps x (hi,lo) in regs
    bf16x8 cfh_r[16], cfl_r[16];
    #pragma unroll
    for (int t = 0; t < 16; ++t) {
        cfh_r[t] = cfh[(t*4 + w)*64 + lane];
        cfl_r[t] = cfl[(t*4 + w)*64 + lane];
    }

    f32x4 acc[4][8];
    #pragma unroll
    for (int i = 0; i < 4; ++i)
        #pragma unroll
        for (int j = 0; j < 8; ++j) acc[i][j] = (f32x4){0.f, 0.f, 0.f, 0.f};
    float rs = 0.f;
    const int qs = (q ^ (q << 2)) << 4;            // lane's swizzle component

    for (int ch = 0; ch < CPB; ++ch) {
        // ---- stage: rows w*8..w*8+7, convert f32 -> packed (hi,lo) pairs ----
        {
            const size_t rbase = n0 + (size_t)ch * 32 + w * 8;
            #pragma unroll
            for (int half = 0; half < 2; ++half) {
                float4 vv[8];
                #pragma unroll
                for (int rr = 0; rr < 8; ++rr)
                    vv[rr] = *(const float4*)(x + (rbase + rr) * D_ + half*256 + lane*4);
                #pragma unroll
                for (int rr = 0; rr < 8; ++rr) {
                    const int row = w*8 + rr;
                    uint4 pq;
                    pq.x = pack_hi2(vv[rr].x, vv[rr].x - trunc_hi(vv[rr].x));
                    pq.y = pack_hi2(vv[rr].y, vv[rr].y - trunc_hi(vv[rr].y));
                    pq.z = pack_hi2(vv[rr].z, vv[rr].z - trunc_hi(vv[rr].z));
                    pq.w = pack_hi2(vv[rr].w, vv[rr].w - trunc_hi(vv[rr].w));
                    *(uint4*)((char*)xp + row*2048 +
                              ((half*1024 + lane*16) ^ xswb2(row))) = pq;
                }
            }
        }
        __syncthreads();

        // ===================== logits: 32 tok x 16 cols (c-tile w) ==========
        f32x4 lacc[2];
        lacc[0] = (f32x4){0.f,0.f,0.f,0.f};
        lacc[1] = (f32x4){0.f,0.f,0.f,0.f};
        #pragma unroll
        for (int t = 0; t < 16; ++t) {
            #pragma unroll
            for (int mt = 0; mt < 2; ++mt) {
                const int tokA = mt*16 + li;
                const char* xrow = (const char*)xp + tokA * 2048;
                const int swbA = xswb2(tokA);
                const int lin = t*128 + q*32;
                const uint4 p0 = *(const uint4*)(xrow + ( lin       ^ swbA));
                const uint4 p1 = *(const uint4*)(xrow + ((lin + 16) ^ swbA));
                U8 ah, al;
                ah.u[0] = lo16s(p0.x, p0.y); ah.u[1] = lo16s(p0.z, p0.w);
                ah.u[2] = lo16s(p1.x, p1.y); ah.u[3] = lo16s(p1.z, p1.w);
                al.u[0] = hi16s(p0.x, p0.y); al.u[1] = hi16s(p0.z, p0.w);
                al.u[2] = hi16s(p1.x, p1.y); al.u[3] = hi16s(p1.z, p1.w);
                lacc[mt] = __builtin_amdgcn_mfma_f32_16x16x32_bf16(ah.v, cfh_r[t], lacc[mt], 0, 0, 0);
                lacc[mt] = __builtin_amdgcn_mfma_f32_16x16x32_bf16(ah.v, cfl_r[t], lacc[mt], 0, 0, 0);
                lacc[mt] = __builtin_amdgcn_mfma_f32_16x16x32_bf16(al.v, cfh_r[t], lacc[mt], 0, 0, 0);
            }
        }

        // ===================== softmax =====================
        float er[2][4];
        #pragma unroll
        for (int mt = 0; mt < 2; ++mt)
            #pragma unroll
            for (int reg = 0; reg < 4; ++reg) {
                const float lg = fmaf(lacc[mt][reg], alpha, beta);
                const float e = __expf(lg);
                er[mt][reg] = e;
                float s0 = e;
                s0 += __shfl_xor(s0, 1);
                s0 += __shfl_xor(s0, 2);
                s0 += __shfl_xor(s0, 4);
                s0 += __shfl_xor(s0, 8);
                if (li == 0) red[mt*16 + q*4 + reg][w] = s0;
            }
        __syncthreads();
        #pragma unroll
        for (int mt = 0; mt < 2; ++mt) {
            u32 prr[4];
            #pragma unroll
            for (int reg = 0; reg < 4; ++reg) {
                const int tok = mt*16 + q*4 + reg;
                const float4 r4 = *(const float4*)&red[tok][0];
                const float inv = 1.0f / (r4.x + r4.y + r4.z + r4.w);
                const float a = er[mt][reg] * inv;
                rs += a;
                prr[reg] = pack_hi2(a, a - trunc_hi(a));
            }
            *(uint4*)((char*)at + col*144 + (mt*16 + q*4)*4) =
                make_uint4(prr[0], prr[1], prr[2], prr[3]);
        }
        __syncthreads();

        // ===================== vlad accumulate =====================
        bf16x8 ah2[4], al2[4];
        #pragma unroll
        for (int mtv = 0; mtv < 4; ++mtv) {
            const char* arow = (const char*)at + (mtv*16 + li)*144 + q*32;
            const uint4 p0 = *(const uint4*)(arow);
            const uint4 p1 = *(const uint4*)(arow + 16);
            U8 uh, ul;
            uh.u[0] = lo16s(p0.x, p0.y); uh.u[1] = lo16s(p0.z, p0.w);
            uh.u[2] = lo16s(p1.x, p1.y); uh.u[3] = lo16s(p1.z, p1.w);
            ul.u[0] = hi16s(p0.x, p0.y); ul.u[1] = hi16s(p0.z, p0.w);
            ul.u[2] = hi16s(p1.x, p1.y); ul.u[3] = hi16s(p1.z, p1.w);
            ah2[mtv] = uh.v; al2[mtv] = ul.v;
        }
        const char* xq = (const char*)xp + q * 16384;   // q-quarter row base
        #pragma unroll
        for (int nt = 0; nt < 8; ++nt) {
            const int dcol = w*128 + nt*16 + li;
            const int e = (dcol*4) ^ qs;
            u32 p[8];
            #pragma unroll
            for (int j = 0; j < 8; ++j)
                p[j] = *(const u32*)(xq + j*2048 + (e ^ (j << 4)));
            U8 bh, bl;
            bh.u[0] = lo16s(p[0], p[1]); bh.u[1] = lo16s(p[2], p[3]);
            bh.u[2] = lo16s(p[4], p[5]); bh.u[3] = lo16s(p[6], p[7]);
            bl.u[0] = hi16s(p[0], p[1]); bl.u[1] = hi16s(p[2], p[3]);
            bl.u[2] = hi16s(p[4], p[5]); bl.u[3] = hi16s(p[6], p[7]);
            #pragma unroll
            for (int mtv = 0; mtv < 4; ++mtv) {
                acc[mtv][nt] = __builtin_amdgcn_mfma_f32_16x16x32_bf16(ah2[mtv], bh.v, acc[mtv][nt], 0, 0, 0);
                acc[mtv][nt] = __builtin_amdgcn_mfma_f32_16x16x32_bf16(ah2[mtv], bl.v, acc[mtv][nt], 0, 0, 0);
                acc[mtv][nt] = __builtin_amdgcn_mfma_f32_16x16x32_bf16(al2[mtv], bh.v, acc[mtv][nt], 0, 0, 0);
            }
        }
        __syncthreads();   // xp + at reads done before next stage/at-write
    }

    // ===================== epilogue: part[s][b][d][k], NT float4 stores =====
    float* pp = part + ((size_t)s * B_ + b) * ((size_t)K_ * D_);
    #pragma unroll
    for (int nt = 0; nt < 8; ++nt) {
        const int d = w*128 + nt*16 + li;
        #pragma unroll
        for (int mtv = 0; mtv < 4; ++mtv) {
            __builtin_nontemporal_store(acc[mtv][nt],
                (f32x4*)(pp + (size_t)d * K_ + mtv*16 + q*4));
        }
    }
    // a_sum: rs holds per-lane col sum over its 8 (mt,reg) tokens; reduce q
    rs += __shfl_xor(rs, 16);
    rs += __shfl_xor(rs, 32);
    if (q == 0) atomicAdd(&a_sum[b*K_ + col], rs);
}

// ---------------------------------------------------------------------------
// C1: v[d][k] = sum_s part - a_sum*c2 ; write into part slice 0; ssq per k.
// part layout [s][b][d][k]; c2 is (D,K) contiguous -> coalesced float4.
// Grid (B_, 32): 16 d-rows per block, all 64 k.
// ---------------------------------------------------------------------------
__global__ __launch_bounds__(256) void k_final1(
    const float* __restrict__ part_ro, const float* __restrict__ a_sum,
    const float* __restrict__ c2, float* __restrict__ part0,
    float* __restrict__ ssqk)
{
    const int b = blockIdx.x, dc = blockIdx.y;   // dc 0..31
    const int tid = threadIdx.x;
    const int w = tid >> 6, lane = tid & 63;
    const int q = lane >> 4, li = lane & 15;
    const int k4 = li * 4;
    const int d = dc*16 + w*4 + q;
    const size_t PS = (size_t)B_ * K_ * D_;
    const size_t base = (size_t)b * K_ * D_ + (size_t)d * K_ + k4;
    __shared__ float redk[4][64];

    float4 v = *(const float4*)(part_ro + base);
    #pragma unroll
    for (int ss = 1; ss < NS; ++ss) {
        const float4 p = *(const float4*)(part_ro + (size_t)ss*PS + base);
        v.x += p.x; v.y += p.y; v.z += p.z; v.w += p.w;
    }
    const float4 cv = *(const float4*)(c2 + (size_t)d * K_ + k4);
    const float4 av = *(const float4*)(a_sum + b*K_ + k4);
    v.x = fmaf(-av.x, cv.x, v.x);
    v.y = fmaf(-av.y, cv.y, v.y);
    v.z = fmaf(-av.z, cv.z, v.z);
    v.w = fmaf(-av.w, cv.w, v.w);
    *(float4*)(part0 + base) = v;

    float4 sq = make_float4(v.x*v.x, v.y*v.y, v.z*v.z, v.w*v.w);
    sq.x += __shfl_xor(sq.x, 16); sq.x += __shfl_xor(sq.x, 32);
    sq.y += __shfl_xor(sq.y, 16); sq.y += __shfl_xor(sq.y, 32);
    sq.z += __shfl_xor(sq.z, 16); sq.z += __shfl_xor(sq.z, 32);
    sq.w += __shfl_xor(sq.w, 16); sq.w += __shfl_xor(sq.w, 32);
    if (q == 0) *(float4*)&redk[w][k4] = sq;
    __syncthreads();
    if (tid < 64) {
        const float ssum = redk[0][tid] + redk[1][tid] + redk[2][tid] + redk[3][tid];
        atomicAdd(&ssqk[b*K_ + tid], ssum);
    }
}

// ---------------------------------------------------------------------------
// C2: scale by intra/global inverse norms. part slice0 is already [d][k] =
// the output layout, so this is a pure streaming scale (no transpose).
// Grid (B_, 8).
// ---------------------------------------------------------------------------
__global__ __launch_bounds__(256) void k_final2(
    const float* __restrict__ v0, const float* __restrict__ ssqk,
    float* __restrict__ out)
{
    const int b = blockIdx.x, g = blockIdx.y;    // g 0..7
    const int tid = threadIdx.x;
    __shared__ float invk[64];
    __shared__ float invg_s;

    if (tid < 64) {
        const float ss = ssqk[b*K_ + tid];
        const float inv = 1.0f / fmaxf(sqrtf(ss), 1e-12f);
        invk[tid] = inv;
        float gp = ss * inv * inv;
        #pragma unroll
        for (int m = 1; m < 64; m <<= 1) gp += __shfl_xor(gp, m);
        if (tid == 0) invg_s = 1.0f / fmaxf(sqrtf(gp), 1e-12f);
    }
    __syncthreads();

    const float ig = invg_s;
    const size_t bb = (size_t)b * K_ * D_;
    #pragma unroll
    for (int i = 0; i < 4; ++i) {
        const int f = g*1024 + i*256 + tid;      // float4 index within [d][k]
        const int k4 = (f & 15) * 4;
        const float4 v = *(const float4*)(v0 + bb + (size_t)f * 4);
        const float4 kv = *(const float4*)&invk[k4];
        float4 o;
        o.x = v.x * kv.x * ig;
        o.y = v.y * kv.y * ig;
        o.z = v.z * kv.z * ig;
        o.w = v.w * kv.w * ig;
        *(float4*)(out + bb + (size_t)f * 4) = o;
    }
}

// ---------------------------------------------------------------------------
extern "C" void kernel_launch(void* const* d_in, const int* in_sizes, int n_in,
                              void* d_out, int out_size, void* d_ws, size_t ws_size,
                              hipStream_t stream)
{
    const float* x    = (const float*)d_in[0];
    const float* clus = (const float*)d_in[1];
    const float* c2   = (const float*)d_in[2];
    const float* bnw  = (const float*)d_in[3];
    const float* bnb  = (const float*)d_in[4];
    const float* rm   = (const float*)d_in[5];
    const float* rv   = (const float*)d_in[6];
    float* out = (float*)d_out;

    float* part  = (float*)d_ws;                                 // NS*B_*K_*D_ = 67.1 MB
    float* a_sum = part + (size_t)NS * B_ * K_ * D_;             // B_*K_
    float* ssqk  = a_sum + B_ * K_;                              // B_*K_
    bf16x8* cfh  = (bf16x8*)(ssqk + B_ * K_);                    // 64 KB
    bf16x8* cfl  = cfh + 16*4*64;                                // 64 KB

    hipMemsetAsync(a_sum, 0, 2 * B_ * K_ * sizeof(float), stream);

    k_prep<<<dim3(16, 4), 64, 0, stream>>>(clus, cfh, cfl);
    k_fused<<<dim3(NS, B_), 256, 0, stream>>>(x, cfh, cfl, bnw, bnb, rm, rv, part, a_sum);
    k_final1<<<dim3(B_, 32), 256, 0, stream>>>(part, a_sum, c2, part, ssqk);
    k_final2<<<dim3(B_, 8), 256, 0, stream>>>(part, ssqk, out);
}

// Round 5
// 565.108 us; speedup vs baseline: 1.1224x; 1.1224x over previous
//
#include <hip/hip_runtime.h>
#include <stdint.h>

#define B_ 32
#define N_ 4096
#define D_ 512
#define K_ 64
#define M_ (B_ * N_)        // 131072 total tokens
#define NS 8                // n-splits (blocks per batch) for fused kernel
#define CPB 16              // 32-token chunks per block (512 tokens / 32)

typedef float f32x4 __attribute__((ext_vector_type(4)));
typedef short bf16x8 __attribute__((ext_vector_type(8)));
typedef uint32_t u32;

union U8 { u32 u[4]; bf16x8 v; uint4 q4; };

// low16 = bf16_trunc(a), high16 = bf16_trunc(b)
__device__ __forceinline__ u32 pack_hi2(float a, float b) {
    return __builtin_amdgcn_perm(__float_as_uint(b), __float_as_uint(a), 0x07060302u);
}
// gather low16 halves of (p0,p1) -> u32
__device__ __forceinline__ u32 lo16s(u32 p0, u32 p1) {
    return __builtin_amdgcn_perm(p1, p0, 0x05040100u);
}
// gather high16 halves of (p0,p1) -> u32
__device__ __forceinline__ u32 hi16s(u32 p0, u32 p1) {
    return __builtin_amdgcn_perm(p1, p0, 0x07060302u);
}
__device__ __forceinline__ float trunc_hi(float f) {
    return __uint_as_float(__float_as_uint(f) & 0xffff0000u);
}

// XOR swizzle (16B granule) for the xp tile (bank-balanced for row b128
// reads, column b32 gathers, and staging b128 writes).
__device__ __forceinline__ int xswb2(int tok) {
    return (((tok & 7) ^ (tok >> 3) ^ ((tok >> 3) << 2)) << 4);
}

// raw barrier draining ONLY lgkmcnt — keeps staged global loads in flight.
// All intra-chunk hazards are LDS-only, so this is sufficient.
__device__ __forceinline__ void bar_lgkm() {
    asm volatile("s_waitcnt lgkmcnt(0)" ::: "memory");
    __builtin_amdgcn_sched_barrier(0);
    __builtin_amdgcn_s_barrier();
    __builtin_amdgcn_sched_barrier(0);
    asm volatile("" ::: "memory");
}

// ---------------------------------------------------------------------------
// Prep: clusters (D x K) -> frag-ordered bf16 hi/lo arrays (unchanged).
// cfh/cfl[(t*4 + c)*64 + lane] elem j = B[t*32 + (lane>>4)*8 + j][c*16 + (lane&15)]
// ---------------------------------------------------------------------------
__global__ void k_prep(const float* __restrict__ clusters,
                       bf16x8* __restrict__ cfh, bf16x8* __restrict__ cfl)
{
    const int t = blockIdx.x;        // 0..15 k-chunk (32 wide)
    const int c = blockIdx.y;        // 0..3  col tile (16 wide)
    const int lane = threadIdx.x;    // 0..63
    const int q = lane >> 4, li = lane & 15;
    U8 h, l;
    #pragma unroll
    for (int j2 = 0; j2 < 4; ++j2) {
        float v0 = clusters[(t*32 + q*8 + 2*j2 + 0) * K_ + c*16 + li];
        float v1 = clusters[(t*32 + q*8 + 2*j2 + 1) * K_ + c*16 + li];
        float l0 = v0 - trunc_hi(v0), l1 = v1 - trunc_hi(v1);
        h.u[j2] = pack_hi2(v0, v1);
        l.u[j2] = pack_hi2(l0, l1);
    }
    cfh[(t*4 + c)*64 + lane] = h.v;
    cfl[(t*4 + c)*64 + lane] = l.v;
}

// ---------------------------------------------------------------------------
// Fused kernel, v5: 8 waves / 512 threads, 1 block/CU (2 waves/SIMD).
// Per-wave state fits 256 regs: cf frags split by t-half across wave pairs
// (64 VGPR), vlad acc 64 d per wave (64 AGPR), T14 reg-staging (32 VGPR).
// Wave w: cw = w&3 (c-tile), th = w>>2 (t-half / token-half).
//   logits: partial over t in [th*8, th*8+8) for c-tile cw, both token
//           halves; pairwise sum via LDS exchange; finalize tokens of th.
//   vlad:   d-range [w*64, w*64+64), all 64 k.
//   stage:  rows w*4..w*4+3 (issue loads at chunk top, ds_write at end).
// Grid (NS=8, B_=32) = 256 blocks.
// ---------------------------------------------------------------------------
__global__ __launch_bounds__(512, 2) void k_fused(
    const float* __restrict__ x,
    const bf16x8* __restrict__ cfh, const bf16x8* __restrict__ cfl,
    const float* __restrict__ bnw, const float* __restrict__ bnb,
    const float* __restrict__ rm, const float* __restrict__ rv,
    float* __restrict__ part, float* __restrict__ a_sum)
{
    const int tid  = threadIdx.x;
    const int w    = tid >> 6, lane = tid & 63;
    const int q    = lane >> 4, li = lane & 15;
    const int cw   = w & 3, th = w >> 2;
    const int s    = blockIdx.x, b = blockIdx.y;
    const size_t n0 = (size_t)b * N_ + (size_t)s * (N_ / NS);

    __shared__ __align__(16) u32 xp[32 * 512];     // 64 KB packed pairs, swizzled
    __shared__ __align__(16) u32 at[64 * 36];      // 9 KB aT[k][tok], stride 144 B
    __shared__ __align__(16) f32x4 exch[8][64][2]; // 16 KB logits partial exchange
    __shared__ float red[32][4];                   // per-token partial denoms

    // BN(eval) coefficients: this wave's c-tile, col = cw*16 + li
    const int col = cw*16 + li;
    const float alpha = bnw[col] * rsqrtf(rv[col] + 1e-5f);
    const float beta  = bnb[col] - rm[col] * alpha;

    // cf fragments: this wave's c-tile, t-range [th*8, th*8+8)
    bf16x8 cfh_r[8], cfl_r[8];
    #pragma unroll
    for (int tt = 0; tt < 8; ++tt) {
        cfh_r[tt] = cfh[((th*8 + tt)*4 + cw)*64 + lane];
        cfl_r[tt] = cfl[((th*8 + tt)*4 + cw)*64 + lane];
    }

    f32x4 acc[4][4];
    #pragma unroll
    for (int i = 0; i < 4; ++i)
        #pragma unroll
        for (int j = 0; j < 4; ++j) acc[i][j] = (f32x4){0.f, 0.f, 0.f, 0.f};
    float rs = 0.f;
    const int qs = (q ^ (q << 2)) << 4;            // lane's vlad swizzle part

    // ---- prologue: stage chunk 0 (load -> convert -> write) ----
    float4 sv[8];
    {
        const size_t rbase = n0 + w * 4;
        #pragma unroll
        for (int rr = 0; rr < 4; ++rr)
            #pragma unroll
            for (int half = 0; half < 2; ++half)
                sv[rr*2 + half] = *(const float4*)(x + (rbase + rr) * D_ + half*256 + lane*4);
        #pragma unroll
        for (int rr = 0; rr < 4; ++rr) {
            const int row = w*4 + rr;
            #pragma unroll
            for (int half = 0; half < 2; ++half) {
                const float4 vv = sv[rr*2 + half];
                uint4 pq;
                pq.x = pack_hi2(vv.x, vv.x - trunc_hi(vv.x));
                pq.y = pack_hi2(vv.y, vv.y - trunc_hi(vv.y));
                pq.z = pack_hi2(vv.z, vv.z - trunc_hi(vv.z));
                pq.w = pack_hi2(vv.w, vv.w - trunc_hi(vv.w));
                *(uint4*)((char*)xp + row*2048 +
                          ((half*1024 + lane*16) ^ xswb2(row))) = pq;
            }
        }
    }
    __syncthreads();

    for (int ch = 0; ch < CPB; ++ch) {
        // ---- T14 issue-early: global loads for chunk ch+1 into regs ----
        if (ch + 1 < CPB) {
            const size_t rbase = n0 + (size_t)(ch + 1) * 32 + w * 4;
            #pragma unroll
            for (int rr = 0; rr < 4; ++rr)
                #pragma unroll
                for (int half = 0; half < 2; ++half)
                    sv[rr*2 + half] = *(const float4*)(x + (rbase + rr) * D_ + half*256 + lane*4);
        }

        // ===== logits partial: c-tile cw, t in [th*8,th*8+8), both mt =====
        f32x4 lacc[2];
        lacc[0] = (f32x4){0.f,0.f,0.f,0.f};
        lacc[1] = (f32x4){0.f,0.f,0.f,0.f};
        #pragma unroll
        for (int tt = 0; tt < 8; ++tt) {
            const int t = th*8 + tt;
            #pragma unroll
            for (int mt = 0; mt < 2; ++mt) {
                const int tokA = mt*16 + li;
                const char* xrow = (const char*)xp + tokA * 2048;
                const int swbA = xswb2(tokA);
                const int lin = t*128 + q*32;
                const uint4 p0 = *(const uint4*)(xrow + ( lin       ^ swbA));
                const uint4 p1 = *(const uint4*)(xrow + ((lin + 16) ^ swbA));
                U8 ah, al;
                ah.u[0] = lo16s(p0.x, p0.y); ah.u[1] = lo16s(p0.z, p0.w);
                ah.u[2] = lo16s(p1.x, p1.y); ah.u[3] = lo16s(p1.z, p1.w);
                al.u[0] = hi16s(p0.x, p0.y); al.u[1] = hi16s(p0.z, p0.w);
                al.u[2] = hi16s(p1.x, p1.y); al.u[3] = hi16s(p1.z, p1.w);
                lacc[mt] = __builtin_amdgcn_mfma_f32_16x16x32_bf16(ah.v, cfh_r[tt], lacc[mt], 0, 0, 0);
                lacc[mt] = __builtin_amdgcn_mfma_f32_16x16x32_bf16(ah.v, cfl_r[tt], lacc[mt], 0, 0, 0);
                lacc[mt] = __builtin_amdgcn_mfma_f32_16x16x32_bf16(al.v, cfh_r[tt], lacc[mt], 0, 0, 0);
            }
        }
        exch[w][lane][0] = lacc[0];
        exch[w][lane][1] = lacc[1];
        bar_lgkm();

        // ===== finalize tokens of this wave's th: BN -> exp -> denom =====
        const f32x4 full = lacc[th] + exch[w ^ 4][lane][th];
        float er[4];
        #pragma unroll
        for (int reg = 0; reg < 4; ++reg) {
            const float lg = fmaf(full[reg], alpha, beta);
            const float e = __expf(lg);
            er[reg] = e;
            float s0 = e;
            s0 += __shfl_xor(s0, 1);
            s0 += __shfl_xor(s0, 2);
            s0 += __shfl_xor(s0, 4);
            s0 += __shfl_xor(s0, 8);
            if (li == 0) red[th*16 + q*4 + reg][cw] = s0;
        }
        bar_lgkm();
        {
            u32 prr[4];
            #pragma unroll
            for (int reg = 0; reg < 4; ++reg) {
                const int tok = th*16 + q*4 + reg;
                const float4 r4 = *(const float4*)&red[tok][0];
                const float inv = 1.0f / (r4.x + r4.y + r4.z + r4.w);
                const float a = er[reg] * inv;
                rs += a;
                prr[reg] = pack_hi2(a, a - trunc_hi(a));
            }
            *(uint4*)((char*)at + col*144 + (th*16 + q*4)*4) =
                make_uint4(prr[0], prr[1], prr[2], prr[3]);
        }
        bar_lgkm();

        // ===== vlad accumulate: d-range [w*64, w*64+64), all 64 k =====
        bf16x8 ah2[4], al2[4];
        #pragma unroll
        for (int mtv = 0; mtv < 4; ++mtv) {
            const char* arow = (const char*)at + (mtv*16 + li)*144 + q*32;
            const uint4 p0 = *(const uint4*)(arow);
            const uint4 p1 = *(const uint4*)(arow + 16);
            U8 uh, ul;
            uh.u[0] = lo16s(p0.x, p0.y); uh.u[1] = lo16s(p0.z, p0.w);
            uh.u[2] = lo16s(p1.x, p1.y); uh.u[3] = lo16s(p1.z, p1.w);
            ul.u[0] = hi16s(p0.x, p0.y); ul.u[1] = hi16s(p0.z, p0.w);
            ul.u[2] = hi16s(p1.x, p1.y); ul.u[3] = hi16s(p1.z, p1.w);
            ah2[mtv] = uh.v; al2[mtv] = ul.v;
        }
        const char* xq = (const char*)xp + q * 16384;   // q-quarter row base
        #pragma unroll
        for (int nt = 0; nt < 4; ++nt) {
            const int dcol = w*64 + nt*16 + li;
            const int e = (dcol*4) ^ qs;
            u32 p[8];
            #pragma unroll
            for (int j = 0; j < 8; ++j)
                p[j] = *(const u32*)(xq + j*2048 + (e ^ (j << 4)));
            U8 bh, bl;
            bh.u[0] = lo16s(p[0], p[1]); bh.u[1] = lo16s(p[2], p[3]);
            bh.u[2] = lo16s(p[4], p[5]); bh.u[3] = lo16s(p[6], p[7]);
            bl.u[0] = hi16s(p[0], p[1]); bl.u[1] = hi16s(p[2], p[3]);
            bl.u[2] = hi16s(p[4], p[5]); bl.u[3] = hi16s(p[6], p[7]);
            #pragma unroll
            for (int mtv = 0; mtv < 4; ++mtv) {
                acc[mtv][nt] = __builtin_amdgcn_mfma_f32_16x16x32_bf16(ah2[mtv], bh.v, acc[mtv][nt], 0, 0, 0);
                acc[mtv][nt] = __builtin_amdgcn_mfma_f32_16x16x32_bf16(ah2[mtv], bl.v, acc[mtv][nt], 0, 0, 0);
                acc[mtv][nt] = __builtin_amdgcn_mfma_f32_16x16x32_bf16(al2[mtv], bh.v, acc[mtv][nt], 0, 0, 0);
            }
        }
        bar_lgkm();   // all xp/at reads complete before restage

        // ---- stage-write chunk ch+1 (waits staged regs via vmcnt-on-use) ----
        if (ch + 1 < CPB) {
            #pragma unroll
            for (int rr = 0; rr < 4; ++rr) {
                const int row = w*4 + rr;
                #pragma unroll
                for (int half = 0; half < 2; ++half) {
                    const float4 vv = sv[rr*2 + half];
                    uint4 pq;
                    pq.x = pack_hi2(vv.x, vv.x - trunc_hi(vv.x));
                    pq.y = pack_hi2(vv.y, vv.y - trunc_hi(vv.y));
                    pq.z = pack_hi2(vv.z, vv.z - trunc_hi(vv.z));
                    pq.w = pack_hi2(vv.w, vv.w - trunc_hi(vv.w));
                    *(uint4*)((char*)xp + row*2048 +
                              ((half*1024 + lane*16) ^ xswb2(row))) = pq;
                }
            }
        }
        bar_lgkm();
    }

    // ===================== epilogue: part[s][b][d][k], NT float4 stores =====
    float* pp = part + ((size_t)s * B_ + b) * ((size_t)K_ * D_);
    #pragma unroll
    for (int nt = 0; nt < 4; ++nt) {
        const int d = w*64 + nt*16 + li;
        #pragma unroll
        for (int mtv = 0; mtv < 4; ++mtv) {
            __builtin_nontemporal_store(acc[mtv][nt],
                (f32x4*)(pp + (size_t)d * K_ + mtv*16 + q*4));
        }
    }
    // a_sum: rs = per-lane col sum over this wave's 16 tokens; reduce q groups
    rs += __shfl_xor(rs, 16);
    rs += __shfl_xor(rs, 32);
    if (q == 0) atomicAdd(&a_sum[b*K_ + col], rs);
}

// ---------------------------------------------------------------------------
// C1: v[d][k] = sum_s part - a_sum*c2 ; write into part slice 0; ssq per k.
// part layout [s][b][d][k]; c2 is (D,K) contiguous -> coalesced float4.
// Grid (B_, 32): 16 d-rows per block, all 64 k.
// ---------------------------------------------------------------------------
__global__ __launch_bounds__(256) void k_final1(
    const float* __restrict__ part_ro, const float* __restrict__ a_sum,
    const float* __restrict__ c2, float* __restrict__ part0,
    float* __restrict__ ssqk)
{
    const int b = blockIdx.x, dc = blockIdx.y;   // dc 0..31
    const int tid = threadIdx.x;
    const int w = tid >> 6, lane = tid & 63;
    const int q = lane >> 4, li = lane & 15;
    const int k4 = li * 4;
    const int d = dc*16 + w*4 + q;
    const size_t PS = (size_t)B_ * K_ * D_;
    const size_t base = (size_t)b * K_ * D_ + (size_t)d * K_ + k4;
    __shared__ float redk[4][64];

    float4 v = *(const float4*)(part_ro + base);
    #pragma unroll
    for (int ss = 1; ss < NS; ++ss) {
        const float4 p = *(const float4*)(part_ro + (size_t)ss*PS + base);
        v.x += p.x; v.y += p.y; v.z += p.z; v.w += p.w;
    }
    const float4 cv = *(const float4*)(c2 + (size_t)d * K_ + k4);
    const float4 av = *(const float4*)(a_sum + b*K_ + k4);
    v.x = fmaf(-av.x, cv.x, v.x);
    v.y = fmaf(-av.y, cv.y, v.y);
    v.z = fmaf(-av.z, cv.z, v.z);
    v.w = fmaf(-av.w, cv.w, v.w);
    *(float4*)(part0 + base) = v;

    float4 sq = make_float4(v.x*v.x, v.y*v.y, v.z*v.z, v.w*v.w);
    sq.x += __shfl_xor(sq.x, 16); sq.x += __shfl_xor(sq.x, 32);
    sq.y += __shfl_xor(sq.y, 16); sq.y += __shfl_xor(sq.y, 32);
    sq.z += __shfl_xor(sq.z, 16); sq.z += __shfl_xor(sq.z, 32);
    sq.w += __shfl_xor(sq.w, 16); sq.w += __shfl_xor(sq.w, 32);
    if (q == 0) *(float4*)&redk[w][k4] = sq;
    __syncthreads();
    if (tid < 64) {
        const float ssum = redk[0][tid] + redk[1][tid] + redk[2][tid] + redk[3][tid];
        atomicAdd(&ssqk[b*K_ + tid], ssum);
    }
}

// ---------------------------------------------------------------------------
// C2: scale by intra/global inverse norms. part slice0 is already [d][k] =
// the output layout, so this is a pure streaming scale (no transpose).
// Grid (B_, 8).
// ---------------------------------------------------------------------------
__global__ __launch_bounds__(256) void k_final2(
    const float* __restrict__ v0, const float* __restrict__ ssqk,
    float* __restrict__ out)
{
    const int b = blockIdx.x, g = blockIdx.y;    // g 0..7
    const int tid = threadIdx.x;
    __shared__ float invk[64];
    __shared__ float invg_s;

    if (tid < 64) {
        const float ss = ssqk[b*K_ + tid];
        const float inv = 1.0f / fmaxf(sqrtf(ss), 1e-12f);
        invk[tid] = inv;
        float gp = ss * inv * inv;
        #pragma unroll
        for (int m = 1; m < 64; m <<= 1) gp += __shfl_xor(gp, m);
        if (tid == 0) invg_s = 1.0f / fmaxf(sqrtf(gp), 1e-12f);
    }
    __syncthreads();

    const float ig = invg_s;
    const size_t bb = (size_t)b * K_ * D_;
    #pragma unroll
    for (int i = 0; i < 4; ++i) {
        const int f = g*1024 + i*256 + tid;      // float4 index within [d][k]
        const int k4 = (f & 15) * 4;
        const float4 v = *(const float4*)(v0 + bb + (size_t)f * 4);
        const float4 kv = *(const float4*)&invk[k4];
        float4 o;
        o.x = v.x * kv.x * ig;
        o.y = v.y * kv.y * ig;
        o.z = v.z * kv.z * ig;
        o.w = v.w * kv.w * ig;
        *(float4*)(out + bb + (size_t)f * 4) = o;
    }
}

// ---------------------------------------------------------------------------
extern "C" void kernel_launch(void* const* d_in, const int* in_sizes, int n_in,
                              void* d_out, int out_size, void* d_ws, size_t ws_size,
                              hipStream_t stream)
{
    const float* x    = (const float*)d_in[0];
    const float* clus = (const float*)d_in[1];
    const float* c2   = (const float*)d_in[2];
    const float* bnw  = (const float*)d_in[3];
    const float* bnb  = (const float*)d_in[4];
    const float* rm   = (const float*)d_in[5];
    const float* rv   = (const float*)d_in[6];
    float* out = (float*)d_out;

    float* part  = (float*)d_ws;                                 // NS*B_*K_*D_ = 33.5 MB
    float* a_sum = part + (size_t)NS * B_ * K_ * D_;             // B_*K_
    float* ssqk  = a_sum + B_ * K_;                              // B_*K_
    bf16x8* cfh  = (bf16x8*)(ssqk + B_ * K_);                    // 64 KB
    bf16x8* cfl  = cfh + 16*4*64;                                // 64 KB

    hipMemsetAsync(a_sum, 0, 2 * B_ * K_ * sizeof(float), stream);

    k_prep<<<dim3(16, 4), 64, 0, stream>>>(clus, cfh, cfl);
    k_fused<<<dim3(NS, B_), 512, 0, stream>>>(x, cfh, cfl, bnw, bnb, rm, rv, part, a_sum);
    k_final1<<<dim3(B_, 32), 256, 0, stream>>>(part, a_sum, c2, part, ssqk);
    k_final2<<<dim3(B_, 8), 256, 0, stream>>>(part, ssqk, out);
}